// Round 1
// baseline (2725.467 us; speedup 1.0000x reference)
//
#include <hip/hip_runtime.h>

// ---------------------------------------------------------------------------
// head3 R4: templated gconv (compile-time NTAPS/KPER), fully-unrolled
// (tap,ks) phase loop with B-fragment register double-buffer so the
// compiler emits counted s_waitcnt vmcnt(N) instead of per-tap drains.
// setprio(1) around each MFMA cluster (2 waves/SIMD, phase-drifted).
// Everything else (layouts, epilogue, apply/head kernels) unchanged.
// ---------------------------------------------------------------------------

#define NPOS 324
#define NPIX 32768

typedef __attribute__((ext_vector_type(8))) short short8;     // 8 bf16
typedef __attribute__((ext_vector_type(8))) unsigned short us8;
typedef __attribute__((ext_vector_type(4))) float f32x4;

#define AS1 __attribute__((address_space(1)))
#define AS3 __attribute__((address_space(3)))

__device__ __forceinline__ void atomicAddF(float* p, float v) {
    __hip_atomic_fetch_add(p, v, __ATOMIC_RELAXED, __HIP_MEMORY_SCOPE_AGENT);
}
__device__ __forceinline__ unsigned short f2b(float f) {  // fp32 -> bf16 RNE
    unsigned u = __builtin_bit_cast(unsigned, f);
    u = u + 0x7fffu + ((u >> 16) & 1u);
    return (unsigned short)(u >> 16);
}
__device__ __forceinline__ float b2f(unsigned short h) {
    unsigned u = ((unsigned)h) << 16;
    return __builtin_bit_cast(float, u);
}

// ---------------------------------------------------------------------------
// gconv: raw[pix][384](bf16, pre-BN, n<324 only) = sum_taps A_shift @ W_tap.
// Block: 64 pixels (2 rows), 256 thr (4 waves: wn 0..3 over 21 n-tiles 6/5/5/5).
// Per k-stage (64 k): A halo (4 rows x 34 cols, XOR-swizzled 16B cells) via
// global_load_lds, double-buffered. Compute = 2*NTAPS unrolled phases; each
// phase prefetches the NEXT phase's B fragments (register dbuf) before its
// own MFMAs -> B loads stay in flight across the MFMA clusters (vmcnt(6)).
// ---------------------------------------------------------------------------
template<int NTAPS, int KPER>
__global__ __launch_bounds__(256, 2) void k_gconv(
    const unsigned short* __restrict__ in,   // bf16 [NPIX][KPER]
    const unsigned short* __restrict__ W,    // bf16 [NTAPS][KGPER][336][8]
    unsigned short* __restrict__ raw,        // bf16 [NPIX][384] pre-BN out
    float* __restrict__ stats,               // [2][324]
    const unsigned short* __restrict__ zb)   // zeros
{
    constexpr bool HALO   = (NTAPS != 1);
    constexpr int  NCHUNK = HALO ? 1088 : 512;   // halo 136 pix vs 64 pix, x8 cells
    constexpr int  NSTAGE = KPER >> 6;
    constexpr int  KGPER  = KPER >> 3;
    constexpr int  NPH    = 2 * NTAPS;

    __shared__ __align__(16) unsigned short Ab[2][NCHUNK * 8];
    __shared__ float slds[672];

    const int tid = threadIdx.x;
    const int wv  = tid >> 6;
    const int L   = tid & 63;
    const int q   = L >> 4;
    const int l15 = L & 15;
    const int ntcnt = (wv == 0) ? 6 : 5;
    const int nt0   = (wv == 0) ? 0 : 6 + 5 * (wv - 1);

    const int blk  = blockIdx.x;
    const int pix0 = blk * 64;
    const int b    = blk >> 4;
    const int h0   = (blk & 15) * 2;

    for (int i = tid; i < 672; i += 256) slds[i] = 0.f;

    const f32x4 fzero = {0.f, 0.f, 0.f, 0.f};
    f32x4 acc[4][6];
#pragma unroll
    for (int i = 0; i < 4; ++i)
#pragma unroll
        for (int j = 0; j < 6; ++j) acc[i][j] = fzero;

    // ---- A stage DMA (wave-uniform LDS base + lane*16B; swizzled global src)
    auto stageA = [&](int sbuf, int kc0) {
#pragma unroll
        for (int it = 0; it < (NCHUNK + 255) / 256; ++it) {
            const int c = it * 256 + tid;
            if (c < NCHUNK) {
                const int pixp = c >> 3;
                const int g = (c & 7) ^ (pixp & 7);
                const unsigned short* gp;
                if (HALO) {
                    const int hr = pixp / 34, wc = pixp - hr * 34;
                    const int hh = h0 + hr - 1, ww = wc - 1;
                    if ((unsigned)hh < 32u && (unsigned)ww < 32u)
                        gp = in + (size_t)((b * 32 + hh) * 32 + ww) * KPER + kc0 + g * 8;
                    else
                        gp = zb + g * 8;
                } else {
                    gp = in + (size_t)(pix0 + pixp) * KPER + kc0 + g * 8;
                }
                __builtin_amdgcn_global_load_lds(
                    (AS1 const unsigned short*)(uintptr_t)gp,
                    (AS3 unsigned short*)(&Ab[sbuf][0] + (it * 256 + wv * 64) * 8),
                    16, 0, 0);
            }
        }
    };

    stageA(0, 0);
    __syncthreads();

    for (int stage = 0; stage < NSTAGE; ++stage) {
        const int cur = stage & 1;
        if (stage + 1 < NSTAGE) stageA(1 - cur, (stage + 1) << 6);

        const unsigned short* Wst = W + (size_t)(stage * 8) * 336 * 8;

        short8 bcur[6], bnxt[6];
        auto loadB = [&](short8* dst, int ph) {
            const int tap = ph >> 1, ks = ph & 1;
            const int g = ks * 4 + q;
            const unsigned short* wp =
                Wst + ((size_t)(tap * KGPER + g) * 336 + nt0 * 16 + l15) * 8;
#pragma unroll
            for (int j = 0; j < 6; ++j)
                if (j < ntcnt) dst[j] = *(const short8*)(wp + j * 128);
        };

        loadB(bcur, 0);

#pragma unroll
        for (int ph = 0; ph < NPH; ++ph) {
            const int tap = ph >> 1, ks = ph & 1;
            const int di = HALO ? (tap / 3 - 1) : 0;
            const int dj = HALO ? (tap % 3 - 1) : 0;
            const int g = ks * 4 + q;

            // A fragments for this phase (LDS, short latency)
            short8 a[4];
#pragma unroll
            for (int i = 0; i < 4; ++i) {
                const int m = i * 16 + l15;
                int pixp;
                if (HALO) {
                    pixp = ((m >> 5) + di + 1) * 34 + (m & 31) + dj + 1;
                } else {
                    pixp = m;
                }
                const int cell = pixp * 8 + (g ^ (pixp & 7));
                a[i] = *(const short8*)(&Ab[cur][0] + cell * 8);
            }

            // prefetch next phase's B fragments (stay in flight across MFMAs)
            if (ph + 1 < NPH) loadB(bnxt, ph + 1);

            __builtin_amdgcn_s_setprio(1);
#pragma unroll
            for (int i = 0; i < 4; ++i)
#pragma unroll
                for (int j = 0; j < 6; ++j)
                    if (j < ntcnt)
                        acc[i][j] = __builtin_amdgcn_mfma_f32_16x16x32_bf16(
                            a[i], bcur[j], acc[i][j], 0, 0, 0);
            __builtin_amdgcn_s_setprio(0);

#pragma unroll
            for (int j = 0; j < 6; ++j)
                if (j < ntcnt) bcur[j] = bnxt[j];
        }
        __syncthreads();
    }

    // ---- epilogue: bf16 raw store + per-column (sum, sumsq)
#pragma unroll
    for (int j = 0; j < 6; ++j) {
        if (j < ntcnt) {
            const int n = (nt0 + j) * 16 + l15;
            float s1 = 0.f, s2 = 0.f;
#pragma unroll
            for (int i = 0; i < 4; ++i) {
#pragma unroll
                for (int r = 0; r < 4; ++r) {
                    const float v = acc[i][j][r];
                    s1 += v; s2 += v * v;
                    if (n < NPOS)
                        raw[(size_t)(pix0 + i * 16 + q * 4 + r) * 384 + n] = f2b(v);
                }
            }
            s1 += __shfl_xor(s1, 16); s1 += __shfl_xor(s1, 32);
            s2 += __shfl_xor(s2, 16); s2 += __shfl_xor(s2, 32);
            if (L < 16 && n < NPOS) {
                atomicAdd(&slds[n], s1);
                atomicAdd(&slds[336 + n], s2);
            }
        }
    }
    __syncthreads();
    for (int i = tid; i < 648; i += 256) {
        const int rowi = i / 324, n = i - rowi * 324;
        atomicAddF(&stats[rowi * 324 + n], slds[rowi * 336 + n]);
    }
}

// ---------------------------------------------------------------------------
// x (b,c,p,q,y,w) fp32 -> Xr[(b,y,w)][c*256+p*16+q] bf16.
// ---------------------------------------------------------------------------
__global__ __launch_bounds__(256) void k_xr(
    const float* __restrict__ x, unsigned short* __restrict__ Xr)
{
    __shared__ float Xs[256 * 33];
    const int t = threadIdx.x;
    const int blk = blockIdx.x;
    const int y = blk & 31;
    const int bc = blk >> 5;
    const int c = bc & 7;
    const int bi = bc >> 3;
    const float* xb = x + (size_t)bc * 262144;
    {
        const int w = t & 31, ph = t >> 5;
        for (int it = 0; it < 32; ++it) {
            const int pq = it * 8 + ph;
            Xs[pq * 33 + w] = xb[(size_t)pq * 1024 + y * 32 + w];
        }
    }
    __syncthreads();
    const int w = t >> 3, gg = t & 7;
    unsigned short* orow = Xr + ((size_t)((bi * 32 + y) * 32 + w)) * 2048 + c * 256;
#pragma unroll
    for (int sub = 0; sub < 4; ++sub) {
        const int pq0 = gg * 32 + sub * 8;
        short8 o;
#pragma unroll
        for (int e = 0; e < 8; ++e) o[e] = (short)f2b(Xs[(pq0 + e) * 33 + w]);
        *(short8*)(orow + pq0) = o;
    }
}

// ---------------------------------------------------------------------------
// W packs (B-fragment order [tap][kg][n][8k], 16B cells)
// ---------------------------------------------------------------------------
__global__ __launch_bounds__(256) void k_pw0(
    const float* __restrict__ U0, const float* __restrict__ V0,
    unsigned short* __restrict__ Wp)
{
    const int t = blockIdx.x * 256 + threadIdx.x;
    if (t >= 9 * 256 * 336) return;
    const int n = t % 336;
    const int kgg = (t / 336) & 255;
    const int tap = t / (336 * 256);
    short8 o = {0, 0, 0, 0, 0, 0, 0, 0};
    if (n < NPOS) {
        const int aa = n / 18, d = n % 18;
#pragma unroll
        for (int j = 0; j < 8; ++j) {
            const int k = kgg * 8 + j;
            const int c = k >> 8, p = (k >> 4) & 15, qq = k & 15;
            const float u = U0[((size_t)(c * 9 + tap) * 18 + aa) * 16 + p];
            const float v = V0[((size_t)(c * 9 + tap) * 16 + qq) * 18 + d];
            o[j] = (short)f2b(u * v);
        }
    }
    *(short8*)(Wp + (size_t)t * 8) = o;
}

__global__ __launch_bounds__(256) void k_pw1(
    const float* __restrict__ U1, const float* __restrict__ V1,
    unsigned short* __restrict__ Wp)
{
    const int t = blockIdx.x * 256 + threadIdx.x;
    if (t >= 9 * 48 * 336) return;
    const int n = t % 336;
    const int kgg = (t / 336) % 48;
    const int cv = t / (336 * 48);
    short8 o = {0, 0, 0, 0, 0, 0, 0, 0};
    if (n < NPOS) {
        const int aa = n / 18, d = n % 18;
#pragma unroll
        for (int j = 0; j < 8; ++j) {
            const int k = kgg * 8 + j;
            if (k < NPOS) {
                const int p = k / 18, qq = k % 18;
                o[j] = (short)f2b(U1[cv * 324 + aa * 18 + p] * V1[cv * 324 + qq * 18 + d]);
            }
        }
    }
    *(short8*)(Wp + (size_t)t * 8) = o;
}

__global__ __launch_bounds__(256) void k_pw3(
    const float* __restrict__ U3, const float* __restrict__ V3,
    unsigned short* __restrict__ Wp)
{
    const int t = blockIdx.x * 256 + threadIdx.x;
    if (t >= 27 * 48 * 336) return;
    const int n = t % 336;
    const int kgg = (t / 336) % 48;
    const int e = t / (336 * 48);    // c3*9 + tap
    short8 o = {0, 0, 0, 0, 0, 0, 0, 0};
    if (n < NPOS) {
        const int aa = n / 18, d = n % 18;
#pragma unroll
        for (int j = 0; j < 8; ++j) {
            const int k = kgg * 8 + j;
            if (k < NPOS) {
                const int p = k / 18, qq = k % 18;
                o[j] = (short)f2b(U3[(size_t)e * 324 + aa * 18 + p] * V3[(size_t)e * 324 + qq * 18 + d]);
            }
        }
    }
    *(short8*)(Wp + (size_t)t * 8) = o;
}

// ---------------------------------------------------------------------------
// applyA: out(bf16) = PReLU?(sc*raw + sh); pads (cols>=324) zeroed.
// ---------------------------------------------------------------------------
__global__ __launch_bounds__(256) void k_applyA(
    const unsigned short* __restrict__ rawp, const float* __restrict__ st,
    const float* __restrict__ gamma, const float* __restrict__ beta,
    const float* __restrict__ alpha, const int aidx,
    unsigned short* __restrict__ outp)
{
    __shared__ float sc[NPOS], sh[NPOS];
    const int t = threadIdx.x;
    for (int i = t; i < NPOS; i += 256) {
        const float m = st[i] * (1.f / 32768.f);
        float v = st[NPOS + i] * (1.f / 32768.f) - m * m;
        v = fmaxf(v, 0.f);
        const float s = gamma[i] * rsqrtf(v + 1e-5f);
        sc[i] = s;
        sh[i] = beta[i] - m * s;
    }
    __syncthreads();
    const float a = (aidx >= 0) ? alpha[aidx] : 0.f;
    for (int idx = blockIdx.x * 256 + t; idx < NPIX * 48; idx += gridDim.x * 256) {
        const int grp = idx % 48;
        const int c0 = grp * 8;
        us8 o;
        if (c0 < NPOS) {
            const us8 x = *(const us8*)(rawp + (size_t)idx * 8);
#pragma unroll
            for (int e = 0; e < 8; ++e) {
                const int col = c0 + e;
                float r = 0.f;
                if (col < NPOS) {
                    const float v = b2f(x[e]);
                    r = sc[col] * v + sh[col];
                    if (aidx >= 0) r = r >= 0.f ? r : a * r;
                }
                o[e] = f2b(r);
            }
        } else {
            o = (us8){0, 0, 0, 0, 0, 0, 0, 0};
        }
        *(us8*)(outp + (size_t)idx * 8) = o;
    }
}

// ---------------------------------------------------------------------------
// applyR: out(bf16) = (scA*rawA+shA) + (scB*rawB+shB); pads zeroed.
// ---------------------------------------------------------------------------
__global__ __launch_bounds__(256) void k_applyR(
    const unsigned short* __restrict__ rawA, const float* __restrict__ stA,
    const float* __restrict__ gA, const float* __restrict__ bA,
    const unsigned short* __restrict__ rawB, const float* __restrict__ stB,
    const float* __restrict__ gB, const float* __restrict__ bB,
    unsigned short* __restrict__ outp)
{
    __shared__ float scA[NPOS], shA[NPOS], scB[NPOS], shB[NPOS];
    const int t = threadIdx.x;
    for (int i = t; i < NPOS; i += 256) {
        float m = stA[i] * (1.f / 32768.f);
        float v = fmaxf(stA[NPOS + i] * (1.f / 32768.f) - m * m, 0.f);
        float s = gA[i] * rsqrtf(v + 1e-5f);
        scA[i] = s; shA[i] = bA[i] - m * s;
        m = stB[i] * (1.f / 32768.f);
        v = fmaxf(stB[NPOS + i] * (1.f / 32768.f) - m * m, 0.f);
        s = gB[i] * rsqrtf(v + 1e-5f);
        scB[i] = s; shB[i] = bB[i] - m * s;
    }
    __syncthreads();
    for (int idx = blockIdx.x * 256 + t; idx < NPIX * 48; idx += gridDim.x * 256) {
        const int grp = idx % 48;
        const int c0 = grp * 8;
        us8 o;
        if (c0 < NPOS) {
            const us8 xa = *(const us8*)(rawA + (size_t)idx * 8);
            const us8 xb = *(const us8*)(rawB + (size_t)idx * 8);
#pragma unroll
            for (int e = 0; e < 8; ++e) {
                const int col = c0 + e;
                float r = 0.f;
                if (col < NPOS) {
                    r = (scA[col] * b2f(xa[e]) + shA[col])
                      + (scB[col] * b2f(xb[e]) + shB[col]);
                }
                o[e] = f2b(r);
            }
        } else {
            o = (us8){0, 0, 0, 0, 0, 0, 0, 0};
        }
        *(us8*)(outp + (size_t)idx * 8) = o;
    }
}

// ---------------------------------------------------------------------------
// fcn head: out[b,o,h,w] = sum_n x31[pix][n] Wf[o][n] + bf[o]   (x31 bf16)
// ---------------------------------------------------------------------------
__global__ __launch_bounds__(320) void k_head(
    const unsigned short* __restrict__ in, const float* __restrict__ Wf,
    const float* __restrict__ bfv, float* __restrict__ out)
{
    __shared__ float Ts[32 * 325];
    const int t = threadIdx.x;
    const int bh = blockIdx.x;
    const int b = bh >> 5, h = bh & 31;
    const unsigned short* src = in + (size_t)bh * 32 * 384;
    for (int k = t; k < 32 * NPOS; k += 320) {
        const int pl = k / NPOS, col = k - pl * NPOS;
        Ts[pl * 325 + col] = b2f(src[(size_t)pl * 384 + col]);
    }
    __syncthreads();
    const int o = t >> 5, w = t & 31;
    float s = bfv[o];
    const float* wrow = Wf + o * NPOS;
    const float* trow = Ts + w * 325;
#pragma unroll 4
    for (int k = 0; k < NPOS; ++k) s += trow[k] * wrow[k];
    out[(size_t)((b * 10 + o) * 32 + h) * 32 + w] = s;
}

// ---------------------------------------------------------------------------
extern "C" void kernel_launch(void* const* d_in, const int* in_sizes, int n_in,
                              void* d_out, int out_size, void* d_ws, size_t ws_size,
                              hipStream_t stream)
{
    (void)in_sizes; (void)n_in; (void)out_size; (void)ws_size;
    const float* x  = (const float*)d_in[0];
    const float* U0 = (const float*)d_in[1];
    const float* V0 = (const float*)d_in[2];
    const float* U1 = (const float*)d_in[4];
    const float* V1 = (const float*)d_in[5];
    const float* U3 = (const float*)d_in[7];
    const float* V3 = (const float*)d_in[8];
    const float* Wf = (const float*)d_in[10];
    const float* bf = (const float*)d_in[11];
    const float* g  = (const float*)d_in[12];
    const float* be = (const float*)d_in[13];
    const float* al = (const float*)d_in[14];
    float* out = (float*)d_out;

    const size_t NB = (size_t)NPIX * 384;    // bf16 buffer elems
    float* st = (float*)d_ws;                                  // 13*648 f
    unsigned short* ZB  = (unsigned short*)(st + 13 * 648);    // 4KB zeros
    unsigned short* Xr  = ZB + 2048;                           // [NPIX][2048]
    unsigned short* W0p = Xr + (size_t)NPIX * 2048;
    unsigned short* W1p = W0p + (size_t)9 * 256 * 336 * 8;
    unsigned short* W3p = W1p + (size_t)9 * 48 * 336 * 8;
    unsigned short* Rt   = W3p + (size_t)27 * 48 * 336 * 8;
    unsigned short* Rid1 = Rt + NB;
    unsigned short* Rid2 = Rid1 + NB;
    unsigned short* H    = Rid2 + NB;
    unsigned short* T    = H + NB;
    unsigned short* T2   = T + NB;
    unsigned short* X1   = T2 + NB;
    unsigned short* X2   = X1 + NB;
    unsigned short* X3   = X2 + NB;

    hipMemsetAsync(st, 0, 13 * 648 * sizeof(float), stream);
    hipMemsetAsync(ZB, 0, 4096, stream);

    k_xr<<<8192, 256, 0, stream>>>(x, Xr);
    k_pw0<<<(9 * 256 * 336) / 256, 256, 0, stream>>>(U0, V0, W0p);
    k_pw1<<<(9 * 48 * 336 + 255) / 256, 256, 0, stream>>>(U1, V1, W1p);
    k_pw3<<<(27 * 48 * 336 + 255) / 256, 256, 0, stream>>>(U3, V3, W3p);

    #define ST(k) (st + (k) * 648)
    #define G(k)  (g  + (k) * NPOS)
    #define BE(k) (be + (k) * NPOS)
    #define W1C(k) (W1p + (size_t)(k) * 48 * 336 * 8)
    #define W3C(k) (W3p + (size_t)(k) * 9 * 48 * 336 * 8)

    // f0
    k_gconv<9, 2048><<<512, 256, 0, stream>>>(Xr, W0p, Rt, ST(0), ZB);
    k_applyA<<<2048, 256, 0, stream>>>(Rt, ST(0), G(0), BE(0), al, 0, H);
    // s1 identity (raw kept) + block11
    k_gconv<1, 384><<<512, 256, 0, stream>>>(H, W1C(0), Rid1, ST(1), ZB);
    k_gconv<1, 384><<<512, 256, 0, stream>>>(H, W1C(1), Rt, ST(2), ZB);
    k_applyA<<<2048, 256, 0, stream>>>(Rt, ST(2), G(2), BE(2), al, 1, T);
    k_gconv<9, 384><<<512, 256, 0, stream>>>(T, W3C(0), Rt, ST(3), ZB);
    k_applyA<<<2048, 256, 0, stream>>>(Rt, ST(3), G(3), BE(3), al, 2, T2);
    k_gconv<1, 384><<<512, 256, 0, stream>>>(T2, W1C(2), Rt, ST(4), ZB);
    k_applyR<<<2048, 256, 0, stream>>>(Rt, ST(4), G(4), BE(4),
                                       Rid1, ST(1), G(1), BE(1), X1);   // x11
    // s2 identity (raw kept through block31) + block21
    k_gconv<1, 384><<<512, 256, 0, stream>>>(X1, W1C(3), Rid2, ST(5), ZB);
    k_gconv<1, 384><<<512, 256, 0, stream>>>(X1, W1C(4), Rt, ST(6), ZB);
    k_applyA<<<2048, 256, 0, stream>>>(Rt, ST(6), G(6), BE(6), al, 3, T);
    k_gconv<9, 384><<<512, 256, 0, stream>>>(T, W3C(1), Rt, ST(7), ZB);
    k_applyA<<<2048, 256, 0, stream>>>(Rt, ST(7), G(7), BE(7), al, 4, T2);
    k_gconv<1, 384><<<512, 256, 0, stream>>>(T2, W1C(5), Rt, ST(8), ZB);
    k_applyR<<<2048, 256, 0, stream>>>(Rt, ST(8), G(8), BE(8),
                                       Rid2, ST(5), G(5), BE(5), X2);   // x21
    // block31 (bug-faithful: reuses s2 identity; U1[6]/gamma[9] dead)
    k_gconv<1, 384><<<512, 256, 0, stream>>>(X2, W1C(7), Rt, ST(10), ZB);
    k_applyA<<<2048, 256, 0, stream>>>(Rt, ST(10), G(10), BE(10), al, 5, T);
    k_gconv<9, 384><<<512, 256, 0, stream>>>(T, W3C(2), Rt, ST(11), ZB);
    k_applyA<<<2048, 256, 0, stream>>>(Rt, ST(11), G(11), BE(11), al, 6, T2);
    k_gconv<1, 384><<<512, 256, 0, stream>>>(T2, W1C(8), Rt, ST(12), ZB);
    k_applyR<<<2048, 256, 0, stream>>>(Rt, ST(12), G(12), BE(12),
                                       Rid2, ST(5), G(5), BE(5), X3);   // x31
    // head
    k_head<<<1024, 320, 0, stream>>>(X3, Wf, bf, out);

    #undef ST
    #undef G
    #undef BE
    #undef W1C
    #undef W3C
}

// Round 2
// 2456.274 us; speedup vs baseline: 1.1096x; 1.1096x over previous
//
#include <hip/hip_runtime.h>

// ---------------------------------------------------------------------------
// head3 R5: gconv with B staged through LDS via global_load_lds DMA
// (depth-1 pipeline, counted vmcnt, dual raw s_barrier per phase).
// B prefetch costs ZERO VGPRs (fixes R4's spill). A halo staging unchanged.
// ---------------------------------------------------------------------------

#define NPOS 324
#define NPIX 32768

typedef __attribute__((ext_vector_type(8))) short short8;     // 8 bf16
typedef __attribute__((ext_vector_type(8))) unsigned short us8;
typedef __attribute__((ext_vector_type(4))) float f32x4;

#define AS1 __attribute__((address_space(1)))
#define AS3 __attribute__((address_space(3)))

#define VMCNT(n) asm volatile("s_waitcnt vmcnt(" #n ")" ::: "memory")

__device__ __forceinline__ void atomicAddF(float* p, float v) {
    __hip_atomic_fetch_add(p, v, __ATOMIC_RELAXED, __HIP_MEMORY_SCOPE_AGENT);
}
__device__ __forceinline__ unsigned short f2b(float f) {  // fp32 -> bf16 RNE
    unsigned u = __builtin_bit_cast(unsigned, f);
    u = u + 0x7fffu + ((u >> 16) & 1u);
    return (unsigned short)(u >> 16);
}
__device__ __forceinline__ float b2f(unsigned short h) {
    unsigned u = ((unsigned)h) << 16;
    return __builtin_bit_cast(float, u);
}

// ---------------------------------------------------------------------------
// gconv: raw[pix][384](bf16, pre-BN, n<324 only) = sum_taps A_shift @ W_tap.
// Block: 64 pixels (2 rows), 256 thr (4 waves over 21 n-tiles 6/5/5/5).
// A: halo tile (136 pix x 64k, XOR-swizzled 16B cells) in LDS, dbuf per stage.
// B: per-(tap,ks) slice (336n x 32k = 21504 B) in LDS, dbuf per PHASE,
//    staged by global_load_lds one phase ahead. Layout cell = n_cell*4 + q
//    -> each fragment read is a contiguous 1KiB (conflict-free ds_read_b128).
// Phase: {vmcnt(B(p) landed); s_barrier; ds_read A+B; issue DMA B(p+1);
//         setprio(1) MFMA setprio(0); s_barrier}.
// vmcnt counts are wave-uniform: staging loops have explicit wv==0 tails.
// ---------------------------------------------------------------------------
template<int NTAPS, int KPER>
__global__ __launch_bounds__(256, 2) void k_gconv(
    const unsigned short* __restrict__ in,   // bf16 [NPIX][KPER]
    const unsigned short* __restrict__ W,    // bf16 [NTAPS][KGPER][336][8]
    unsigned short* __restrict__ raw,        // bf16 [NPIX][384] pre-BN out
    float* __restrict__ stats,               // [2][324]
    const unsigned short* __restrict__ zb)   // zeros
{
    constexpr bool HALO   = (NTAPS != 1);
    constexpr int  NCHUNK = HALO ? 1088 : 512;   // A cells (136 or 64 pix x 8)
    constexpr int  NSTAGE = KPER >> 6;
    constexpr int  KGPER  = KPER >> 3;
    constexpr int  NPH    = 2 * NTAPS;           // phases per stage (even)

    __shared__ __align__(16) unsigned short Ab[2][NCHUNK * 8];
    __shared__ __align__(16) unsigned short Bb[2][1344 * 8];   // 336n x 4q cells
    __shared__ float slds[672];

    const int tid = threadIdx.x;
    const int wv  = tid >> 6;
    const int L   = tid & 63;
    const int q   = L >> 4;
    const int l15 = L & 15;
    const int ntcnt = (wv == 0) ? 6 : 5;
    const int nt0   = (wv == 0) ? 0 : 6 + 5 * (wv - 1);

    const int blk  = blockIdx.x;
    const int pix0 = blk * 64;
    const int b    = blk >> 4;
    const int h0   = (blk & 15) * 2;

    for (int i = tid; i < 672; i += 256) slds[i] = 0.f;

    const f32x4 fzero = {0.f, 0.f, 0.f, 0.f};
    f32x4 acc[4][6];
#pragma unroll
    for (int i = 0; i < 4; ++i)
#pragma unroll
        for (int j = 0; j < 6; ++j) acc[i][j] = fzero;

    // ---- single A-cell DMA (dest linear; source XOR-swizzled per lane)
    auto aOne = [&](int sbuf, int c, int kc0, int cellbase) {
        const int pixp = c >> 3;
        const int g = (c & 7) ^ (pixp & 7);
        const unsigned short* gp;
        if (HALO) {
            const int hr = pixp / 34, wc = pixp - hr * 34;
            const int hh = h0 + hr - 1, ww = wc - 1;
            if ((unsigned)hh < 32u && (unsigned)ww < 32u)
                gp = in + (size_t)((b * 32 + hh) * 32 + ww) * KPER + kc0 + g * 8;
            else
                gp = zb + g * 8;
        } else {
            gp = in + (size_t)(pix0 + pixp) * KPER + kc0 + g * 8;
        }
        __builtin_amdgcn_global_load_lds(
            (AS1 const unsigned short*)(uintptr_t)gp,
            (AS3 unsigned short*)(&Ab[sbuf][0] + (size_t)(cellbase + wv * 64) * 8),
            16, 0, 0);
    };
    // A stage: halo = 4 instrs/thread + 1 extra on wave 0; 1x1 = 2 uniform.
    auto stageA = [&](int sbuf, int kc0) {
        if (HALO) {
#pragma unroll
            for (int it = 0; it < 4; ++it) aOne(sbuf, it * 256 + tid, kc0, it * 256);
            if (wv == 0) aOne(sbuf, 1024 + L, kc0, 1024);
        } else {
#pragma unroll
            for (int it = 0; it < 2; ++it) aOne(sbuf, it * 256 + tid, kc0, it * 256);
        }
    };

    // ---- single B-cell DMA: cell c -> (qloc = c&3, ncell = c>>2)
    auto bOne = [&](int buf, int c, const unsigned short* wbase, int cellbase) {
        const int qloc = c & 3, ncell = c >> 2;
        const unsigned short* gp = wbase + ((size_t)qloc * 336 + ncell) * 8;
        __builtin_amdgcn_global_load_lds(
            (AS1 const unsigned short*)(uintptr_t)gp,
            (AS3 unsigned short*)(&Bb[buf][0] + (size_t)(cellbase + wv * 64) * 8),
            16, 0, 0);
    };
    // B stage: 1344 cells = 5 instrs/thread + 1 extra on wave 0.
    auto stageB = [&](int buf, int tap, int ks, int stg) {
        const unsigned short* wbase =
            W + ((size_t)(tap * KGPER + stg * 8 + ks * 4) * 336) * 8;
#pragma unroll
        for (int it = 0; it < 5; ++it) bOne(buf, it * 256 + tid, wbase, it * 256);
        if (wv == 0) bOne(buf, 1280 + L, wbase, 1280);
    };

    // ---- prologue: A(stage0) + B(phase0)
    stageA(0, 0);
    stageB(0, 0, 0, 0);

    for (int stage = 0; stage < NSTAGE; ++stage) {
        const int cur = stage & 1;

#pragma unroll
        for (int ph = 0; ph < NPH; ++ph) {
            const int tap = ph >> 1, ks = ph & 1;
            const int di = HALO ? (tap / 3 - 1) : 0;
            const int dj = HALO ? (tap % 3 - 1) : 0;

            // (1) wait: B(ph) landed. Steady state vmcnt(0) (only B(ph) is
            // outstanding). At ph==1 keep the A-DMA (issued in ph0) in flight.
            if (ph == 1 && stage + 1 < NSTAGE) {
                if (HALO) { if (wv == 0) VMCNT(5); else VMCNT(4); }
                else VMCNT(2);
            } else {
                VMCNT(0);
            }
            __builtin_amdgcn_s_barrier();

            // (2) ds_read fragments
            short8 a[4];
#pragma unroll
            for (int i = 0; i < 4; ++i) {
                const int m = i * 16 + l15;
                int pixp;
                if (HALO) {
                    pixp = ((m >> 5) + di + 1) * 34 + (m & 31) + dj + 1;
                } else {
                    pixp = m;
                }
                const int g = ks * 4 + q;
                const int cell = pixp * 8 + (g ^ (pixp & 7));
                a[i] = *(const short8*)(&Ab[cur][0] + cell * 8);
            }
            short8 bfr[6];
#pragma unroll
            for (int j = 0; j < 6; ++j)
                if (j < ntcnt)
                    bfr[j] = *(const short8*)(
                        &Bb[ph & 1][0] +
                        (size_t)((((nt0 + j) * 16 + l15) * 4 + q)) * 8);

            // (3) issue next DMA (other B buffer; A for next stage at ph0)
            if (ph + 1 < NPH) {
                stageB((ph + 1) & 1, (ph + 1) >> 1, (ph + 1) & 1, stage);
            } else if (stage + 1 < NSTAGE) {
                stageB(0, 0, 0, stage + 1);
            }
            if (ph == 0 && stage + 1 < NSTAGE) {
                stageA(1 - cur, (stage + 1) << 6);
            }

            // (4) MFMA cluster
            __builtin_amdgcn_s_setprio(1);
#pragma unroll
            for (int i = 0; i < 4; ++i)
#pragma unroll
                for (int j = 0; j < 6; ++j)
                    if (j < ntcnt)
                        acc[i][j] = __builtin_amdgcn_mfma_f32_16x16x32_bf16(
                            a[i], bfr[j], acc[i][j], 0, 0, 0);
            __builtin_amdgcn_s_setprio(0);

            // (5) all waves done reading this phase's buffers
            __builtin_amdgcn_s_barrier();
        }
    }

    // ---- epilogue: bf16 raw store + per-column (sum, sumsq)
#pragma unroll
    for (int j = 0; j < 6; ++j) {
        if (j < ntcnt) {
            const int n = (nt0 + j) * 16 + l15;
            float s1 = 0.f, s2 = 0.f;
#pragma unroll
            for (int i = 0; i < 4; ++i) {
#pragma unroll
                for (int r = 0; r < 4; ++r) {
                    const float v = acc[i][j][r];
                    s1 += v; s2 += v * v;
                    if (n < NPOS)
                        raw[(size_t)(pix0 + i * 16 + q * 4 + r) * 384 + n] = f2b(v);
                }
            }
            s1 += __shfl_xor(s1, 16); s1 += __shfl_xor(s1, 32);
            s2 += __shfl_xor(s2, 16); s2 += __shfl_xor(s2, 32);
            if (L < 16 && n < NPOS) {
                atomicAdd(&slds[n], s1);
                atomicAdd(&slds[336 + n], s2);
            }
        }
    }
    __syncthreads();
    for (int i = tid; i < 648; i += 256) {
        const int rowi = i / 324, n = i - rowi * 324;
        atomicAddF(&stats[rowi * 324 + n], slds[rowi * 336 + n]);
    }
}

// ---------------------------------------------------------------------------
// x (b,c,p,q,y,w) fp32 -> Xr[(b,y,w)][c*256+p*16+q] bf16.
// ---------------------------------------------------------------------------
__global__ __launch_bounds__(256) void k_xr(
    const float* __restrict__ x, unsigned short* __restrict__ Xr)
{
    __shared__ float Xs[256 * 33];
    const int t = threadIdx.x;
    const int blk = blockIdx.x;
    const int y = blk & 31;
    const int bc = blk >> 5;
    const int c = bc & 7;
    const int bi = bc >> 3;
    const float* xb = x + (size_t)bc * 262144;
    {
        const int w = t & 31, ph = t >> 5;
        for (int it = 0; it < 32; ++it) {
            const int pq = it * 8 + ph;
            Xs[pq * 33 + w] = xb[(size_t)pq * 1024 + y * 32 + w];
        }
    }
    __syncthreads();
    const int w = t >> 3, gg = t & 7;
    unsigned short* orow = Xr + ((size_t)((bi * 32 + y) * 32 + w)) * 2048 + c * 256;
#pragma unroll
    for (int sub = 0; sub < 4; ++sub) {
        const int pq0 = gg * 32 + sub * 8;
        short8 o;
#pragma unroll
        for (int e = 0; e < 8; ++e) o[e] = (short)f2b(Xs[(pq0 + e) * 33 + w]);
        *(short8*)(orow + pq0) = o;
    }
}

// ---------------------------------------------------------------------------
// W packs (B-fragment order [tap][kg][n][8k], 16B cells)
// ---------------------------------------------------------------------------
__global__ __launch_bounds__(256) void k_pw0(
    const float* __restrict__ U0, const float* __restrict__ V0,
    unsigned short* __restrict__ Wp)
{
    const int t = blockIdx.x * 256 + threadIdx.x;
    if (t >= 9 * 256 * 336) return;
    const int n = t % 336;
    const int kgg = (t / 336) & 255;
    const int tap = t / (336 * 256);
    short8 o = {0, 0, 0, 0, 0, 0, 0, 0};
    if (n < NPOS) {
        const int aa = n / 18, d = n % 18;
#pragma unroll
        for (int j = 0; j < 8; ++j) {
            const int k = kgg * 8 + j;
            const int c = k >> 8, p = (k >> 4) & 15, qq = k & 15;
            const float u = U0[((size_t)(c * 9 + tap) * 18 + aa) * 16 + p];
            const float v = V0[((size_t)(c * 9 + tap) * 16 + qq) * 18 + d];
            o[j] = (short)f2b(u * v);
        }
    }
    *(short8*)(Wp + (size_t)t * 8) = o;
}

__global__ __launch_bounds__(256) void k_pw1(
    const float* __restrict__ U1, const float* __restrict__ V1,
    unsigned short* __restrict__ Wp)
{
    const int t = blockIdx.x * 256 + threadIdx.x;
    if (t >= 9 * 48 * 336) return;
    const int n = t % 336;
    const int kgg = (t / 336) % 48;
    const int cv = t / (336 * 48);
    short8 o = {0, 0, 0, 0, 0, 0, 0, 0};
    if (n < NPOS) {
        const int aa = n / 18, d = n % 18;
#pragma unroll
        for (int j = 0; j < 8; ++j) {
            const int k = kgg * 8 + j;
            if (k < NPOS) {
                const int p = k / 18, qq = k % 18;
                o[j] = (short)f2b(U1[cv * 324 + aa * 18 + p] * V1[cv * 324 + qq * 18 + d]);
            }
        }
    }
    *(short8*)(Wp + (size_t)t * 8) = o;
}

__global__ __launch_bounds__(256) void k_pw3(
    const float* __restrict__ U3, const float* __restrict__ V3,
    unsigned short* __restrict__ Wp)
{
    const int t = blockIdx.x * 256 + threadIdx.x;
    if (t >= 27 * 48 * 336) return;
    const int n = t % 336;
    const int kgg = (t / 336) % 48;
    const int e = t / (336 * 48);    // c3*9 + tap
    short8 o = {0, 0, 0, 0, 0, 0, 0, 0};
    if (n < NPOS) {
        const int aa = n / 18, d = n % 18;
#pragma unroll
        for (int j = 0; j < 8; ++j) {
            const int k = kgg * 8 + j;
            if (k < NPOS) {
                const int p = k / 18, qq = k % 18;
                o[j] = (short)f2b(U3[(size_t)e * 324 + aa * 18 + p] * V3[(size_t)e * 324 + qq * 18 + d]);
            }
        }
    }
    *(short8*)(Wp + (size_t)t * 8) = o;
}

// ---------------------------------------------------------------------------
// applyA: out(bf16) = PReLU?(sc*raw + sh); pads (cols>=324) zeroed.
// ---------------------------------------------------------------------------
__global__ __launch_bounds__(256) void k_applyA(
    const unsigned short* __restrict__ rawp, const float* __restrict__ st,
    const float* __restrict__ gamma, const float* __restrict__ beta,
    const float* __restrict__ alpha, const int aidx,
    unsigned short* __restrict__ outp)
{
    __shared__ float sc[NPOS], sh[NPOS];
    const int t = threadIdx.x;
    for (int i = t; i < NPOS; i += 256) {
        const float m = st[i] * (1.f / 32768.f);
        float v = st[NPOS + i] * (1.f / 32768.f) - m * m;
        v = fmaxf(v, 0.f);
        const float s = gamma[i] * rsqrtf(v + 1e-5f);
        sc[i] = s;
        sh[i] = beta[i] - m * s;
    }
    __syncthreads();
    const float a = (aidx >= 0) ? alpha[aidx] : 0.f;
    for (int idx = blockIdx.x * 256 + t; idx < NPIX * 48; idx += gridDim.x * 256) {
        const int grp = idx % 48;
        const int c0 = grp * 8;
        us8 o;
        if (c0 < NPOS) {
            const us8 x = *(const us8*)(rawp + (size_t)idx * 8);
#pragma unroll
            for (int e = 0; e < 8; ++e) {
                const int col = c0 + e;
                float r = 0.f;
                if (col < NPOS) {
                    const float v = b2f(x[e]);
                    r = sc[col] * v + sh[col];
                    if (aidx >= 0) r = r >= 0.f ? r : a * r;
                }
                o[e] = f2b(r);
            }
        } else {
            o = (us8){0, 0, 0, 0, 0, 0, 0, 0};
        }
        *(us8*)(outp + (size_t)idx * 8) = o;
    }
}

// ---------------------------------------------------------------------------
// applyR: out(bf16) = (scA*rawA+shA) + (scB*rawB+shB); pads zeroed.
// ---------------------------------------------------------------------------
__global__ __launch_bounds__(256) void k_applyR(
    const unsigned short* __restrict__ rawA, const float* __restrict__ stA,
    const float* __restrict__ gA, const float* __restrict__ bA,
    const unsigned short* __restrict__ rawB, const float* __restrict__ stB,
    const float* __restrict__ gB, const float* __restrict__ bB,
    unsigned short* __restrict__ outp)
{
    __shared__ float scA[NPOS], shA[NPOS], scB[NPOS], shB[NPOS];
    const int t = threadIdx.x;
    for (int i = t; i < NPOS; i += 256) {
        float m = stA[i] * (1.f / 32768.f);
        float v = fmaxf(stA[NPOS + i] * (1.f / 32768.f) - m * m, 0.f);
        float s = gA[i] * rsqrtf(v + 1e-5f);
        scA[i] = s; shA[i] = bA[i] - m * s;
        m = stB[i] * (1.f / 32768.f);
        v = fmaxf(stB[NPOS + i] * (1.f / 32768.f) - m * m, 0.f);
        s = gB[i] * rsqrtf(v + 1e-5f);
        scB[i] = s; shB[i] = bB[i] - m * s;
    }
    __syncthreads();
    for (int idx = blockIdx.x * 256 + t; idx < NPIX * 48; idx += gridDim.x * 256) {
        const int grp = idx % 48;
        const int c0 = grp * 8;
        us8 o;
        if (c0 < NPOS) {
            const us8 xa = *(const us8*)(rawA + (size_t)idx * 8);
            const us8 xb = *(const us8*)(rawB + (size_t)idx * 8);
#pragma unroll
            for (int e = 0; e < 8; ++e) {
                const int col = c0 + e;
                float r = 0.f;
                if (col < NPOS) {
                    r = (scA[col] * b2f(xa[e]) + shA[col])
                      + (scB[col] * b2f(xb[e]) + shB[col]);
                }
                o[e] = f2b(r);
            }
        } else {
            o = (us8){0, 0, 0, 0, 0, 0, 0, 0};
        }
        *(us8*)(outp + (size_t)idx * 8) = o;
    }
}

// ---------------------------------------------------------------------------
// fcn head: out[b,o,h,w] = sum_n x31[pix][n] Wf[o][n] + bf[o]   (x31 bf16)
// ---------------------------------------------------------------------------
__global__ __launch_bounds__(320) void k_head(
    const unsigned short* __restrict__ in, const float* __restrict__ Wf,
    const float* __restrict__ bfv, float* __restrict__ out)
{
    __shared__ float Ts[32 * 325];
    const int t = threadIdx.x;
    const int bh = blockIdx.x;
    const int b = bh >> 5, h = bh & 31;
    const unsigned short* src = in + (size_t)bh * 32 * 384;
    for (int k = t; k < 32 * NPOS; k += 320) {
        const int pl = k / NPOS, col = k - pl * NPOS;
        Ts[pl * 325 + col] = b2f(src[(size_t)pl * 384 + col]);
    }
    __syncthreads();
    const int o = t >> 5, w = t & 31;
    float s = bfv[o];
    const float* wrow = Wf + o * NPOS;
    const float* trow = Ts + w * 325;
#pragma unroll 4
    for (int k = 0; k < NPOS; ++k) s += trow[k] * wrow[k];
    out[(size_t)((b * 10 + o) * 32 + h) * 32 + w] = s;
}

// ---------------------------------------------------------------------------
extern "C" void kernel_launch(void* const* d_in, const int* in_sizes, int n_in,
                              void* d_out, int out_size, void* d_ws, size_t ws_size,
                              hipStream_t stream)
{
    (void)in_sizes; (void)n_in; (void)out_size; (void)ws_size;
    const float* x  = (const float*)d_in[0];
    const float* U0 = (const float*)d_in[1];
    const float* V0 = (const float*)d_in[2];
    const float* U1 = (const float*)d_in[4];
    const float* V1 = (const float*)d_in[5];
    const float* U3 = (const float*)d_in[7];
    const float* V3 = (const float*)d_in[8];
    const float* Wf = (const float*)d_in[10];
    const float* bf = (const float*)d_in[11];
    const float* g  = (const float*)d_in[12];
    const float* be = (const float*)d_in[13];
    const float* al = (const float*)d_in[14];
    float* out = (float*)d_out;

    const size_t NB = (size_t)NPIX * 384;    // bf16 buffer elems
    float* st = (float*)d_ws;                                  // 13*648 f
    unsigned short* ZB  = (unsigned short*)(st + 13 * 648);    // 4KB zeros
    unsigned short* Xr  = ZB + 2048;                           // [NPIX][2048]
    unsigned short* W0p = Xr + (size_t)NPIX * 2048;
    unsigned short* W1p = W0p + (size_t)9 * 256 * 336 * 8;
    unsigned short* W3p = W1p + (size_t)9 * 48 * 336 * 8;
    unsigned short* Rt   = W3p + (size_t)27 * 48 * 336 * 8;
    unsigned short* Rid1 = Rt + NB;
    unsigned short* Rid2 = Rid1 + NB;
    unsigned short* H    = Rid2 + NB;
    unsigned short* T    = H + NB;
    unsigned short* T2   = T + NB;
    unsigned short* X1   = T2 + NB;
    unsigned short* X2   = X1 + NB;
    unsigned short* X3   = X2 + NB;

    hipMemsetAsync(st, 0, 13 * 648 * sizeof(float), stream);
    hipMemsetAsync(ZB, 0, 4096, stream);

    k_xr<<<8192, 256, 0, stream>>>(x, Xr);
    k_pw0<<<(9 * 256 * 336) / 256, 256, 0, stream>>>(U0, V0, W0p);
    k_pw1<<<(9 * 48 * 336 + 255) / 256, 256, 0, stream>>>(U1, V1, W1p);
    k_pw3<<<(27 * 48 * 336 + 255) / 256, 256, 0, stream>>>(U3, V3, W3p);

    #define ST(k) (st + (k) * 648)
    #define G(k)  (g  + (k) * NPOS)
    #define BE(k) (be + (k) * NPOS)
    #define W1C(k) (W1p + (size_t)(k) * 48 * 336 * 8)
    #define W3C(k) (W3p + (size_t)(k) * 9 * 48 * 336 * 8)

    // f0
    k_gconv<9, 2048><<<512, 256, 0, stream>>>(Xr, W0p, Rt, ST(0), ZB);
    k_applyA<<<2048, 256, 0, stream>>>(Rt, ST(0), G(0), BE(0), al, 0, H);
    // s1 identity (raw kept) + block11
    k_gconv<1, 384><<<512, 256, 0, stream>>>(H, W1C(0), Rid1, ST(1), ZB);
    k_gconv<1, 384><<<512, 256, 0, stream>>>(H, W1C(1), Rt, ST(2), ZB);
    k_applyA<<<2048, 256, 0, stream>>>(Rt, ST(2), G(2), BE(2), al, 1, T);
    k_gconv<9, 384><<<512, 256, 0, stream>>>(T, W3C(0), Rt, ST(3), ZB);
    k_applyA<<<2048, 256, 0, stream>>>(Rt, ST(3), G(3), BE(3), al, 2, T2);
    k_gconv<1, 384><<<512, 256, 0, stream>>>(T2, W1C(2), Rt, ST(4), ZB);
    k_applyR<<<2048, 256, 0, stream>>>(Rt, ST(4), G(4), BE(4),
                                       Rid1, ST(1), G(1), BE(1), X1);   // x11
    // s2 identity (raw kept through block31) + block21
    k_gconv<1, 384><<<512, 256, 0, stream>>>(X1, W1C(3), Rid2, ST(5), ZB);
    k_gconv<1, 384><<<512, 256, 0, stream>>>(X1, W1C(4), Rt, ST(6), ZB);
    k_applyA<<<2048, 256, 0, stream>>>(Rt, ST(6), G(6), BE(6), al, 3, T);
    k_gconv<9, 384><<<512, 256, 0, stream>>>(T, W3C(1), Rt, ST(7), ZB);
    k_applyA<<<2048, 256, 0, stream>>>(Rt, ST(7), G(7), BE(7), al, 4, T2);
    k_gconv<1, 384><<<512, 256, 0, stream>>>(T2, W1C(5), Rt, ST(8), ZB);
    k_applyR<<<2048, 256, 0, stream>>>(Rt, ST(8), G(8), BE(8),
                                       Rid2, ST(5), G(5), BE(5), X2);   // x21
    // block31 (bug-faithful: reuses s2 identity; U1[6]/gamma[9] dead)
    k_gconv<1, 384><<<512, 256, 0, stream>>>(X2, W1C(7), Rt, ST(10), ZB);
    k_applyA<<<2048, 256, 0, stream>>>(Rt, ST(10), G(10), BE(10), al, 5, T);
    k_gconv<9, 384><<<512, 256, 0, stream>>>(T, W3C(2), Rt, ST(11), ZB);
    k_applyA<<<2048, 256, 0, stream>>>(Rt, ST(11), G(11), BE(11), al, 6, T2);
    k_gconv<1, 384><<<512, 256, 0, stream>>>(T2, W1C(8), Rt, ST(12), ZB);
    k_applyR<<<2048, 256, 0, stream>>>(Rt, ST(12), G(12), BE(12),
                                       Rid2, ST(5), G(5), BE(5), X3);   // x31
    // head
    k_head<<<1024, 320, 0, stream>>>(X3, Wf, bf, out);

    #undef ST
    #undef G
    #undef BE
    #undef W1C
    #undef W3C
}